// Round 5
// baseline (264.143 us; speedup 1.0000x reference)
//
#include <hip/hip_runtime.h>

// TTTConv: fused RMSNorm + depthwise causal conv1d (K=4), f32 in / f32 out.
// B=4, S=4096, H=2048.
// R4 lesson: 6.7 TB/s kernels (fills/copies) are huge grids of short
// straight-line blocks. Long serial per-thread loops stall on vmcnt
// (loads queue behind prior stores). R5: conv pass = one 4-row quad per
// block, straight-line, 7 independent loads -> 4 NT stores, no loops.

#define BQ 4
#define SQ 4096
#define HQ 2048
#define KQ 4
#define ROWS (BQ * SQ)      // 16384

typedef float f32x4 __attribute__((ext_vector_type(4)));

// ---------------- Pass 1: per-row RMS scale -> d_ws ----------------
// One wave per row; 8 independent float4 loads cover H=2048. No LDS/barriers.
__global__ __launch_bounds__(256) void ttt_scale_kernel(
    const float* __restrict__ x,     // [ROWS, H]
    float* __restrict__ sc)          // [ROWS]
{
    const int lane = threadIdx.x & 63;
    const int row  = blockIdx.x * 4 + (threadIdx.x >> 6);

    const float* xr = x + (size_t)row * HQ + lane * 4;

    float4 v[8];
    #pragma unroll
    for (int i = 0; i < 8; ++i)
        v[i] = *reinterpret_cast<const float4*>(xr + i * 256);

    float p = 0.f;
    #pragma unroll
    for (int i = 0; i < 8; ++i)
        p += v[i].x * v[i].x + v[i].y * v[i].y + v[i].z * v[i].z + v[i].w * v[i].w;

    #pragma unroll
    for (int off = 32; off >= 1; off >>= 1)
        p += __shfl_xor(p, off, 64);

    if (lane == 0)
        sc[row] = rsqrtf(p * (1.0f / HQ) + 1e-6f);
}

// ---------------- Pass 2: normalize + causal conv + store ----------------
// One block = one 4-row output quad x full H. Straight-line, no loops.
// 7 independent row loads (quad + 3-row halo), 4 NT stores.
__global__ __launch_bounds__(512) void ttt_conv_kernel(
    const float* __restrict__ x,      // [B,S,H]
    const float* __restrict__ gamma,  // [H]
    const float* __restrict__ cwp,    // [H,1,K]
    const float* __restrict__ cbp,    // [H]
    const float* __restrict__ sc,     // [ROWS] per-row rsqrt scales
    float* __restrict__ out)          // [B,S,H]
{
    const int tid = threadIdx.x;
    const int qpb = SQ / 4;                    // 1024 quads per batch
    const int b   = blockIdx.x / qpb;
    const int s0  = (blockIdx.x % qpb) * 4;    // first output row
    const int h4  = tid * 4;

    const float* xb  = x   + (size_t)b * SQ * HQ + h4;
    float*       ob  = out + (size_t)b * SQ * HQ + h4;
    const float* scb = sc  + (size_t)b * SQ;

    // ---- issue all 7 row loads first: maximum MLP, nothing in front ----
    const float4 f4z = make_float4(0.f, 0.f, 0.f, 0.f);
    float4 v[7];
    #pragma unroll
    for (int i = 0; i < 7; ++i) {
        const int s = s0 - 3 + i;              // uniform per block
        v[i] = (s >= 0) ? *reinterpret_cast<const float4*>(xb + (size_t)s * HQ)
                        : f4z;
    }
    float sv[7];
    #pragma unroll
    for (int i = 0; i < 7; ++i) {
        const int s = s0 - 3 + i;
        sv[i] = (s >= 0) ? scb[s] : 0.f;       // uniform -> scalar loads
    }

    // ---- per-thread constants (L1-resident after first blocks) ----
    const float4 g4    = *reinterpret_cast<const float4*>(gamma + h4);
    const float4 bias4 = *reinterpret_cast<const float4*>(cbp + h4);
    // conv_weight [H,1,K], K=4 -> one float4 per channel; transpose to taps,
    // fold gamma in: o = bias + sum_k (c_k*g) * (x*scale).
    const float4 r0 = *reinterpret_cast<const float4*>(cwp + (size_t)(h4 + 0) * KQ);
    const float4 r1 = *reinterpret_cast<const float4*>(cwp + (size_t)(h4 + 1) * KQ);
    const float4 r2 = *reinterpret_cast<const float4*>(cwp + (size_t)(h4 + 2) * KQ);
    const float4 r3 = *reinterpret_cast<const float4*>(cwp + (size_t)(h4 + 3) * KQ);
    const float4 c0 = make_float4(r0.x * g4.x, r1.x * g4.y, r2.x * g4.z, r3.x * g4.w);
    const float4 c1 = make_float4(r0.y * g4.x, r1.y * g4.y, r2.y * g4.z, r3.y * g4.w);
    const float4 c2 = make_float4(r0.z * g4.x, r1.z * g4.y, r2.z * g4.z, r3.z * g4.w);
    const float4 c3 = make_float4(r0.w * g4.x, r1.w * g4.y, r2.w * g4.z, r3.w * g4.w);

    // ---- scale rows, compute 4 outputs, store ----
    #pragma unroll
    for (int i = 0; i < 7; ++i) {
        v[i].x *= sv[i]; v[i].y *= sv[i]; v[i].z *= sv[i]; v[i].w *= sv[i];
    }

    #pragma unroll
    for (int r = 0; r < 4; ++r) {
        const float4 a = v[r], bb = v[r + 1], c = v[r + 2], d = v[r + 3];
        f32x4 o;
        o.x = bias4.x + c0.x * a.x + c1.x * bb.x + c2.x * c.x + c3.x * d.x;
        o.y = bias4.y + c0.y * a.y + c1.y * bb.y + c2.y * c.y + c3.y * d.y;
        o.z = bias4.z + c0.z * a.z + c1.z * bb.z + c2.z * c.z + c3.z * d.z;
        o.w = bias4.w + c0.w * a.w + c1.w * bb.w + c2.w * c.w + c3.w * d.w;
        __builtin_nontemporal_store(
            o, reinterpret_cast<f32x4*>(ob + (size_t)(s0 + r) * HQ));
    }
}

extern "C" void kernel_launch(void* const* d_in, const int* in_sizes, int n_in,
                              void* d_out, int out_size, void* d_ws, size_t ws_size,
                              hipStream_t stream) {
    const float* x  = (const float*)d_in[0];  // hidden_states [B,S,H] f32
    const float* nw = (const float*)d_in[1];  // norm_weight [H] f32
    const float* cw = (const float*)d_in[2];  // conv_weight [H,1,K] f32
    const float* cb = (const float*)d_in[3];  // conv_bias [H] f32
    float* o  = (float*)d_out;
    float* sc = (float*)d_ws;                 // ROWS floats = 64 KB scratch

    ttt_scale_kernel<<<ROWS / 4, 256, 0, stream>>>(x, sc);
    ttt_conv_kernel<<<BQ * (SQ / 4), 512, 0, stream>>>(x, nw, cw, cb, sc, o);
}